// Round 7
// baseline (57.200 us; speedup 1.0000x reference)
//
#include <hip/hip_runtime.h>
#include <hip/hip_bf16.h>

#define BATCH  8
#define NPTS   4096
#define TPB    256
#define CLOUD  (BATCH * NPTS)      // 32768 points per cloud
#define QTOTAL (2 * CLOUD)         // 65536 outputs

#define QT      8                  // 16-row q-tiles per wave -> 128 q-rows/wave
#define WAVES   4
#define QROWS   (WAVES * QT * 16)  // 512 q-rows per block
#define QCHUNKS (NPTS / QROWS)     // 8
#define RSPLIT  8
#define RPTS    (NPTS / RSPLIT)    // 512 ref points per block
#define JTILES  (RPTS / 16)        // 32

typedef __attribute__((ext_vector_type(8))) short short8;   // 8 bf16 = 1 MFMA frag
typedef __attribute__((ext_vector_type(4))) float f32x4;

// Exact two-term bf16 decomposition: v = hi + lo with both bf16.
__device__ inline void bsplit(float v, ushort& h, ushort& l) {
    __hip_bfloat16 hb = __float2bfloat16(v);
    float hf = __bfloat162float(hb);
    __hip_bfloat16 lb = __float2bfloat16(v - hf);
    h = __builtin_bit_cast(ushort, hb);
    l = __builtin_bit_cast(ushort, lb);
}

#define ONE_BF16 ((ushort)0x3F80)

// Per point, build the K=32 slot vectors (zero-padded past slot 12):
//  A-role (query q): [-2qx_h,-2qx_l,-2qx_h, -2qy_h,-2qy_l,-2qy_h, -2qz_h,-2qz_l,-2qz_h, wq_h,wq_l, 1,1, 0..]
//  B-role (ref   r): [  rx_h,  rx_h,  rx_l,   ry_h,  ry_h,  ry_l,   rz_h,  rz_h,  rz_l,  1,  1, wr_h,wr_l, 0..]
//  dot(A,B) = -2 q.r (exact to ~1e-4) + ||q||^2 + ||r||^2  = d(q,r), finished by the MFMA itself.
__global__ __launch_bounds__(TPB) void nnd_prep(const float* __restrict__ xyz1,
                                                const float* __restrict__ xyz2,
                                                ushort* __restrict__ preA,
                                                ushort* __restrict__ preB) {
    int i = blockIdx.x * TPB + (int)threadIdx.x;       // 0..65535
    const float* src = (i < CLOUD) ? xyz1 : xyz2;
    int j = (i < CLOUD) ? i : i - CLOUD;
    float x = src[3 * j + 0], y = src[3 * j + 1], z = src[3 * j + 2];
    float w = x * x + y * y + z * z;

    ushort axh, axl, ayh, ayl, azh, azl;   // splits of -2*coord (A side)
    ushort bxh, bxl, byh, byl, bzh, bzl;   // splits of coord    (B side)
    ushort wh, wl;
    bsplit(-2.f * x, axh, axl);  bsplit(x, bxh, bxl);
    bsplit(-2.f * y, ayh, ayl);  bsplit(y, byh, byl);
    bsplit(-2.f * z, azh, azl);  bsplit(z, bzh, bzl);
    bsplit(w, wh, wl);

    ushort A[32] = {axh, axl, axh, ayh, ayl, ayh, azh, azl, azh,
                    wh, wl, ONE_BF16, ONE_BF16};          // rest zero
    ushort B[32] = {bxh, bxh, bxl, byh, byh, byl, bzh, bzh, bzl,
                    ONE_BF16, ONE_BF16, wh, wl};          // rest zero

    float4* dA = (float4*)(preA + (size_t)i * 32);
    float4* dB = (float4*)(preB + (size_t)i * 32);
    const float4* sA = (const float4*)A;
    const float4* sB = (const float4*)B;
    #pragma unroll
    for (int k = 0; k < 4; ++k) { dA[k] = sA[k]; dB[k] = sB[k]; }
}

// Main: block = (dir, batch, q-chunk 512, r-split). Each wave owns 128 q-rows
// (8 A-frags in regs), scans 512 ref points as 32 16-col tiles: per tile one
// B-frag global load (L2-hot) + 8 MFMAs, each followed by 4 running v_min.
// C/D layout (verified): col = lane&15, row = (lane>>4)*4 + reg.
__global__ __launch_bounds__(TPB, 3) void nnd_main(const ushort* __restrict__ preA,
                                                   const ushort* __restrict__ preB,
                                                   float* __restrict__ part) {
    const int bid  = blockIdx.x;                  // 1024 blocks
    const int rs   = bid & (RSPLIT - 1);          // 3 bits
    const int qc   = (bid >> 3) & (QCHUNKS - 1);  // 3 bits
    const int b    = (bid >> 6) & (BATCH - 1);    // 3 bits
    const int dir  = bid >> 9;                    // 1 bit

    const int lane = (int)threadIdx.x & 63;
    const int wv   = (int)threadIdx.x >> 6;
    const int col  = lane & 15;
    const int kc   = lane >> 4;                   // k-chunk 0..3

    const ushort* Abase = preA + ((size_t)(dir ? CLOUD : 0) + (size_t)b * NPTS) * 32;
    const ushort* Bbase = preB + ((size_t)(dir ? 0 : CLOUD) + (size_t)b * NPTS) * 32;

    const int qrow0 = qc * QROWS + wv * (QT * 16);
    short8 afrag[QT];
    #pragma unroll
    for (int t = 0; t < QT; ++t)
        afrag[t] = *(const short8*)(Abase + (size_t)(qrow0 + t * 16 + col) * 32 + kc * 8);

    float rmin[QT][4];
    #pragma unroll
    for (int t = 0; t < QT; ++t)
        #pragma unroll
        for (int r = 0; r < 4; ++r) rmin[t][r] = 1e30f;

    const int rbase = rs * RPTS;
    short8 bf = *(const short8*)(Bbase + (size_t)(rbase + col) * 32 + kc * 8);
    for (int jt = 0; jt < JTILES; ++jt) {
        short8 cur = bf;
        if (jt + 1 < JTILES)
            bf = *(const short8*)(Bbase + (size_t)(rbase + (jt + 1) * 16 + col) * 32 + kc * 8);
        #pragma unroll
        for (int t = 0; t < QT; ++t) {
            f32x4 acc = {0.f, 0.f, 0.f, 0.f};
            acc = __builtin_amdgcn_mfma_f32_16x16x32_bf16(afrag[t], cur, acc, 0, 0, 0);
            #pragma unroll
            for (int r = 0; r < 4; ++r) rmin[t][r] = fminf(rmin[t][r], acc[r]);
        }
    }

    // Fold across the 16 columns (lanes with same kc group): xor 1,2,4,8.
    #pragma unroll
    for (int t = 0; t < QT; ++t)
        #pragma unroll
        for (int r = 0; r < 4; ++r) {
            float v = rmin[t][r];
            v = fminf(v, __shfl_xor(v, 1));
            v = fminf(v, __shfl_xor(v, 2));
            v = fminf(v, __shfl_xor(v, 4));
            v = fminf(v, __shfl_xor(v, 8));
            rmin[t][r] = v;
        }

    // Lane (kc*16 + s), s<4 writes row qrow0 + t*16 + kc*4 + s  (static-index select).
    const int s = col;
    float* dst = part + ((size_t)((dir * BATCH + b) * RSPLIT + rs)) * NPTS + qrow0;
    if (s < 4) {
        #pragma unroll
        for (int t = 0; t < QT; ++t) {
            float v = rmin[t][0];
            v = (s == 1) ? rmin[t][1] : v;
            v = (s == 2) ? rmin[t][2] : v;
            v = (s == 3) ? rmin[t][3] : v;
            dst[t * 16 + kc * 4 + s] = v;
        }
    }
}

// Fold the RSPLIT partials per query point.
__global__ __launch_bounds__(TPB) void nnd_reduce(const float* __restrict__ part,
                                                  float* __restrict__ out) {
    int qid = blockIdx.x * TPB + (int)threadIdx.x;     // 0..65535
    int db = qid >> 12;                                // dir*BATCH+b
    int n  = qid & (NPTS - 1);
    const float* p = part + (size_t)db * RSPLIT * NPTS + n;
    float m = p[0];
    #pragma unroll
    for (int r = 1; r < RSPLIT; ++r) m = fminf(m, p[(size_t)r * NPTS]);
    out[qid] = m;
}

extern "C" void kernel_launch(void* const* d_in, const int* in_sizes, int n_in,
                              void* d_out, int out_size, void* d_ws, size_t ws_size,
                              hipStream_t stream) {
    const float* xyz1 = (const float*)d_in[0];
    const float* xyz2 = (const float*)d_in[1];
    ushort* preA = (ushort*)d_ws;                       // 65536 * 64 B = 4 MB
    ushort* preB = preA + (size_t)QTOTAL * 32;          // 4 MB
    float*  part = (float*)(preB + (size_t)QTOTAL * 32);// 2 MB
    float*  out  = (float*)d_out;

    nnd_prep<<<QTOTAL / TPB, TPB, 0, stream>>>(xyz1, xyz2, preA, preB);
    nnd_main<<<2 * BATCH * QCHUNKS * RSPLIT, TPB, 0, stream>>>(preA, preB, part);
    nnd_reduce<<<QTOTAL / TPB, TPB, 0, stream>>>(part, out);
}

// Round 9
// 53.021 us; speedup vs baseline: 1.0788x; 1.0788x over previous
//
#include <hip/hip_runtime.h>
#include <hip/hip_bf16.h>

#define BATCH  8
#define NPTS   4096
#define TPB    256
#define WAVES  4
#define CLOUD  (BATCH * NPTS)       // 32768 points per cloud
#define QTOTAL (2 * CLOUD)          // 65536 outputs

#define QT      4                   // 16-row q-tiles per wave -> 64 q-rows/wave
#define QROWS   (WAVES * QT * 16)   // 256 q-rows per block
#define QCHUNKS (NPTS / QROWS)      // 16
#define RSPLIT  4
#define RPTS    (NPTS / RSPLIT)     // 1024 ref points per block
#define JT      (RPTS / 16)         // 64 column tiles
#define NBLK    (2 * BATCH * QCHUNKS * RSPLIT)  // 1024 blocks

typedef __attribute__((ext_vector_type(8))) short short8;   // 8 bf16 = 1 MFMA frag
typedef __attribute__((ext_vector_type(4))) float f32x4;

// Exact two-term bf16 decomposition: v = hi + lo, both bf16.
__device__ inline void bsplit(float v, ushort& h, ushort& l) {
    __hip_bfloat16 hb = __float2bfloat16(v);
    float hf = __bfloat162float(hb);
    __hip_bfloat16 lb = __float2bfloat16(v - hf);
    h = __builtin_bit_cast(ushort, hb);
    l = __builtin_bit_cast(ushort, lb);
}

#define ONE_BF16 ((ushort)0x3F80)

// K=32 slot encoding (13 used, rest 0); dot(A_q, B_r) = d(q,r) finished by
// the MFMA itself. Validated in round 7 (absmax 7.8e-3).
__global__ __launch_bounds__(TPB) void nnd_prep(const float* __restrict__ xyz1,
                                                const float* __restrict__ xyz2,
                                                ushort* __restrict__ preA,
                                                ushort* __restrict__ preB,
                                                int* __restrict__ out) {
    int i = blockIdx.x * TPB + (int)threadIdx.x;       // 0..65535
    out[i] = 0x7f800000;                               // +inf (re-init every call)

    const float* src = (i < CLOUD) ? xyz1 : xyz2;
    int j = (i < CLOUD) ? i : i - CLOUD;
    float x = src[3 * j + 0], y = src[3 * j + 1], z = src[3 * j + 2];
    float w = x * x + y * y + z * z;

    ushort axh, axl, ayh, ayl, azh, azl;
    ushort bxh, bxl, byh, byl, bzh, bzl;
    ushort wh, wl;
    bsplit(-2.f * x, axh, axl);  bsplit(x, bxh, bxl);
    bsplit(-2.f * y, ayh, ayl);  bsplit(y, byh, byl);
    bsplit(-2.f * z, azh, azl);  bsplit(z, bzh, bzl);
    bsplit(w, wh, wl);

    ushort A[32] = {axh, axl, axh, ayh, ayl, ayh, azh, azl, azh,
                    wh, wl, ONE_BF16, ONE_BF16};
    ushort B[32] = {bxh, bxh, bxl, byh, byh, byl, bzh, bzh, bzl,
                    ONE_BF16, ONE_BF16, wh, wl};

    float4* dA = (float4*)(preA + (size_t)i * 32);
    float4* dB = (float4*)(preB + (size_t)i * 32);
    const float4* sA = (const float4*)A;
    const float4* sB = (const float4*)B;
    #pragma unroll
    for (int k = 0; k < 4; ++k) { dA[k] = sA[k]; dB[k] = sB[k]; }
}

// Main: block = (dir, b, q-chunk 256, r-split 1024). B-frags straight from
// global (L2-hot; validated path from round 7), QT=4 A-frags in regs,
// jt-paired epilogue (compiler forms v_min3), results folded by shfl_xor and
// atomicMin'd into out. C/D layout: col = lane&15, row = (lane>>4)*4 + reg.
__global__ __launch_bounds__(TPB, 4) void nnd_main(const ushort* __restrict__ preA,
                                                   const ushort* __restrict__ preB,
                                                   int* __restrict__ out) {
    // XCD swizzle (bijective: 1024 = 8*128): each XCD gets a contiguous
    // logical slab so (dir,b) working sets stay L2-resident.
    int bid = ((int)blockIdx.x & 7) * (NBLK / 8) + ((int)blockIdx.x >> 3);
    const int rs  = bid & (RSPLIT - 1);           // 2 bits
    const int qc  = (bid >> 2) & (QCHUNKS - 1);   // 4 bits
    const int b   = (bid >> 6) & (BATCH - 1);     // 3 bits
    const int dir = bid >> 9;                     // 1 bit

    const int lane = (int)threadIdx.x & 63;
    const int wv   = (int)threadIdx.x >> 6;
    const int col  = lane & 15;
    const int kc   = lane >> 4;                   // k-chunk 0..3

    const ushort* Abase = preA + ((size_t)(dir ? CLOUD : 0) + (size_t)b * NPTS) * 32;
    const ushort* Bbase = preB + ((size_t)(dir ? 0 : CLOUD) + (size_t)b * NPTS
                                  + (size_t)rs * RPTS) * 32;

    // A-frags: QT tiles of 16 q-rows, 16 B/lane, coalesced.
    const int qrow0 = qc * QROWS + wv * (QT * 16);
    short8 afrag[QT];
    #pragma unroll
    for (int t = 0; t < QT; ++t)
        afrag[t] = *(const short8*)(Abase + (size_t)(qrow0 + t * 16 + col) * 32 + kc * 8);

    float rmin[QT][4];
    #pragma unroll
    for (int t = 0; t < QT; ++t)
        #pragma unroll
        for (int r = 0; r < 4; ++r) rmin[t][r] = 1e30f;

    const f32x4 zero = {0.f, 0.f, 0.f, 0.f};

    // jt-pairs with 1-deep prefetch; per pair: 2 b128 loads + 2*QT MFMA +
    // 4*QT v_min3-able mins.
    const ushort* bp = Bbase + (size_t)col * 32 + kc * 8;
    short8 nb0 = *(const short8*)(bp);
    short8 nb1 = *(const short8*)(bp + 16 * 32);
    for (int jp = 0; jp < JT / 2; ++jp) {
        short8 b0 = nb0, b1 = nb1;
        if (jp + 1 < JT / 2) {
            nb0 = *(const short8*)(bp + (size_t)(jp + 1) * 32 * 32);
            nb1 = *(const short8*)(bp + (size_t)((jp + 1) * 32 + 16) * 32);
        }
        #pragma unroll
        for (int t = 0; t < QT; ++t) {
            f32x4 a0 = __builtin_amdgcn_mfma_f32_16x16x32_bf16(afrag[t], b0, zero, 0, 0, 0);
            f32x4 a1 = __builtin_amdgcn_mfma_f32_16x16x32_bf16(afrag[t], b1, zero, 0, 0, 0);
            #pragma unroll
            for (int r = 0; r < 4; ++r)
                rmin[t][r] = fminf(rmin[t][r], fminf(a0[r], a1[r]));  // -> v_min3
        }
    }

    // Fold across the 16 columns within each kc group.
    #pragma unroll
    for (int t = 0; t < QT; ++t)
        #pragma unroll
        for (int r = 0; r < 4; ++r) {
            float v = rmin[t][r];
            v = fminf(v, __shfl_xor(v, 1));
            v = fminf(v, __shfl_xor(v, 2));
            v = fminf(v, __shfl_xor(v, 4));
            v = fminf(v, __shfl_xor(v, 8));
            rmin[t][r] = v;
        }

    // Lane (kc, s=col<4) owns row qrow0 + t*16 + kc*4 + s. atomicMin combines
    // the RSPLIT partials (non-negative floats: int order == float order;
    // commutative -> deterministic across replays).
    if (col < 4) {
        const int s = col;
        int* o = out + (size_t)dir * CLOUD + (size_t)b * NPTS + qrow0;
        #pragma unroll
        for (int t = 0; t < QT; ++t) {
            float v = rmin[t][0];
            v = (s == 1) ? rmin[t][1] : v;
            v = (s == 2) ? rmin[t][2] : v;
            v = (s == 3) ? rmin[t][3] : v;
            atomicMin(o + t * 16 + kc * 4 + s, __float_as_int(v));
        }
    }
}

extern "C" void kernel_launch(void* const* d_in, const int* in_sizes, int n_in,
                              void* d_out, int out_size, void* d_ws, size_t ws_size,
                              hipStream_t stream) {
    const float* xyz1 = (const float*)d_in[0];
    const float* xyz2 = (const float*)d_in[1];
    ushort* preA = (ushort*)d_ws;                       // 65536 * 64 B = 4 MB
    ushort* preB = preA + (size_t)QTOTAL * 32;          // 4 MB
    int*    out  = (int*)d_out;

    nnd_prep<<<QTOTAL / TPB, TPB, 0, stream>>>(xyz1, xyz2, preA, preB, out);
    nnd_main<<<NBLK, TPB, 0, stream>>>(preA, preB, out);
}

// Round 11
// 38.319 us; speedup vs baseline: 1.4927x; 1.3837x over previous
//
#include <hip/hip_runtime.h>
#include <hip/hip_bf16.h>

#define BATCH  8
#define NPTS   4096
#define TPB    256
#define WAVES  4
#define CLOUD  (BATCH * NPTS)       // 32768 points per cloud
#define QTOTAL (2 * CLOUD)          // 65536 outputs

#define QT      4                   // 16-row q-tiles per wave -> 64 rows/wave
#define QROWS   (WAVES * QT * 16)   // 256 q-rows per block
#define QCHUNKS (NPTS / QROWS)      // 16
#define RSPLIT  8
#define RPTS    (NPTS / RSPLIT)     // 512 ref points per block
#define JT      (RPTS / 16)         // 32 tiles -> 16 pair-iters
#define NBLK    (2 * BATCH * QCHUNKS * RSPLIT)  // 2048 blocks

typedef __attribute__((ext_vector_type(8))) short short8;   // 8 bf16 = 1 frag
typedef __attribute__((ext_vector_type(4))) float f32x4;

// Exact two-term bf16 decomposition: v = hi + lo, both bf16.
__device__ inline void bsplit(float v, ushort& h, ushort& l) {
    __hip_bfloat16 hb = __float2bfloat16(v);
    float hf = __bfloat162float(hb);
    __hip_bfloat16 lb = __float2bfloat16(v - hf);
    h = __builtin_bit_cast(ushort, hb);
    l = __builtin_bit_cast(ushort, lb);
}

#define ONE_BF16 ((ushort)0x3F80)

// K=32 slot encoding (13 used, rest 0): dot(A_q,B_r) = d(q,r) finished by the
// MFMA. Validated rounds 7/9 (absmax 7.8e-3). A stored linearly per point
// (r9 layout, proven). B stored PRE-TRANSPOSED per 512-point chunk in
// [kc][ptl] float4 order so main's LDS staging is a straight copy and LDS
// reads are 2-way-bank (free), no swizzle anywhere.
__global__ __launch_bounds__(TPB) void nnd_prep(const float* __restrict__ xyz1,
                                                const float* __restrict__ xyz2,
                                                ushort* __restrict__ preA,
                                                float4* __restrict__ preB4,
                                                int* __restrict__ out) {
    int i = blockIdx.x * TPB + (int)threadIdx.x;       // 0..65535
    out[i] = 0x7f800000;                               // +inf (re-init every call)

    const int  c   = (i < CLOUD) ? 0 : 1;
    const int  j   = (i < CLOUD) ? i : i - CLOUD;      // point within cloud
    const float* src = c ? xyz2 : xyz1;
    float x = src[3 * j + 0], y = src[3 * j + 1], z = src[3 * j + 2];
    float w = x * x + y * y + z * z;

    ushort axh, axl, ayh, ayl, azh, azl;
    ushort bxh, bxl, byh, byl, bzh, bzl;
    ushort wh, wl;
    bsplit(-2.f * x, axh, axl);  bsplit(x, bxh, bxl);
    bsplit(-2.f * y, ayh, ayl);  bsplit(y, byh, byl);
    bsplit(-2.f * z, azh, azl);  bsplit(z, bzh, bzl);
    bsplit(w, wh, wl);

    ushort A[32] = {axh, axl, axh, ayh, ayl, ayh, azh, azl, azh,
                    wh, wl, ONE_BF16, ONE_BF16};
    ushort B[32] = {bxh, bxh, bxl, byh, byh, byl, bzh, bzh, bzl,
                    ONE_BF16, ONE_BF16, wh, wl};

    // A: linear, 4 float4 per point (r9-proven layout).
    float4* dA = (float4*)(preA + (size_t)i * 32);
    const float4* sA = (const float4*)A;
    #pragma unroll
    for (int k = 0; k < 4; ++k) dA[k] = sA[k];

    // B: [cloud,b][chunk rs][kc][ptl] scatter (4 strided 16B writes).
    const int b   = j >> 12;
    const int p   = j & (NPTS - 1);
    const int rs  = p >> 9;            // chunk of 512
    const int ptl = p & 511;
    const float4* sBv = (const float4*)B;
    float4* dB = preB4 + ((size_t)((c * BATCH + b) * RSPLIT + rs)) * 2048 + ptl;
    #pragma unroll
    for (int kc = 0; kc < 4; ++kc) dB[kc * 512] = sBv[kc];
}

// Main: block = (dir, b, q-chunk 256, r-chunk 512). B chunk staged to LDS by
// straight copy; hot loop touches ONLY LDS (no vmcnt stalls). Epilogue
// verbatim from round 9 (proven). C/D: col=lane&15, row=(lane>>4)*4+reg.
__global__ __launch_bounds__(TPB, 4) void nnd_main(const ushort* __restrict__ preA,
                                                   const float4* __restrict__ preB4,
                                                   int* __restrict__ out) {
    // Bijective XCD swizzle (2048 = 8*256): contiguous logical slab per XCD.
    int bid = ((int)blockIdx.x & 7) * (NBLK / 8) + ((int)blockIdx.x >> 3);
    const int rs  = bid & (RSPLIT - 1);           // 3 bits
    const int qc  = (bid >> 3) & (QCHUNKS - 1);   // 4 bits
    const int b   = (bid >> 7) & (BATCH - 1);     // 3 bits
    const int dir = bid >> 10;                    // 1 bit

    const int lane = (int)threadIdx.x & 63;
    const int wv   = (int)threadIdx.x >> 6;
    const int col  = lane & 15;
    const int kc   = lane >> 4;                   // k-chunk 0..3

    __shared__ float4 sB[RPTS * 4];               // 2048 float4 = 32 KB

    // Stage: straight coalesced copy, conflict-free (consecutive float4s).
    {
        const int cB = dir ? 0 : 1;
        const float4* src = preB4
            + ((size_t)((cB * BATCH + b) * RSPLIT + rs)) * 2048;
        #pragma unroll
        for (int i = 0; i < 8; ++i)
            sB[i * TPB + (int)threadIdx.x] = src[i * TPB + (int)threadIdx.x];
    }

    // A-frags: QT tiles of 16 q-rows, 16 B/lane, coalesced (r9-proven).
    const ushort* Abase = preA + ((size_t)(dir ? CLOUD : 0) + (size_t)b * NPTS) * 32;
    const int qrow0 = qc * QROWS + wv * (QT * 16);
    short8 afrag[QT];
    #pragma unroll
    for (int t = 0; t < QT; ++t)
        afrag[t] = *(const short8*)(Abase + (size_t)(qrow0 + t * 16 + col) * 32 + kc * 8);

    float rmin[QT][4];
    #pragma unroll
    for (int t = 0; t < QT; ++t)
        #pragma unroll
        for (int r = 0; r < 4; ++r) rmin[t][r] = 1e30f;

    const f32x4 zero = {0.f, 0.f, 0.f, 0.f};      // persistent C operand

    __syncthreads();

    // Hot loop: 16 pair-iters of {2 ds_read_b128, 8 MFMA, 16 min}.
    // LDS index u = kc*512 + ptl; tile 2jp -> ptl = jp*32 + col.
    const float4* bp = &sB[kc * 512 + col];
    #pragma unroll 4
    for (int jp = 0; jp < JT / 2; ++jp) {
        short8 b0 = *(const short8*)(bp + jp * 32);
        short8 b1 = *(const short8*)(bp + jp * 32 + 16);
        #pragma unroll
        for (int t = 0; t < QT; ++t) {
            f32x4 a0 = __builtin_amdgcn_mfma_f32_16x16x32_bf16(afrag[t], b0, zero, 0, 0, 0);
            f32x4 a1 = __builtin_amdgcn_mfma_f32_16x16x32_bf16(afrag[t], b1, zero, 0, 0, 0);
            #pragma unroll
            for (int r = 0; r < 4; ++r)
                rmin[t][r] = fminf(rmin[t][r], fminf(a0[r], a1[r]));  // -> v_min3
        }
    }

    // Fold across the 16 columns within each kc group (r9 verbatim).
    #pragma unroll
    for (int t = 0; t < QT; ++t)
        #pragma unroll
        for (int r = 0; r < 4; ++r) {
            float v = rmin[t][r];
            v = fminf(v, __shfl_xor(v, 1));
            v = fminf(v, __shfl_xor(v, 2));
            v = fminf(v, __shfl_xor(v, 4));
            v = fminf(v, __shfl_xor(v, 8));
            rmin[t][r] = v;
        }

    // Lane (kc, s=col<4) owns row qrow0 + t*16 + kc*4 + s (r9 verbatim).
    if (col < 4) {
        const int s = col;
        int* o = out + (size_t)dir * CLOUD + (size_t)b * NPTS + qrow0;
        #pragma unroll
        for (int t = 0; t < QT; ++t) {
            float v = rmin[t][0];
            v = (s == 1) ? rmin[t][1] : v;
            v = (s == 2) ? rmin[t][2] : v;
            v = (s == 3) ? rmin[t][3] : v;
            atomicMin(o + t * 16 + kc * 4 + s, __float_as_int(v));
        }
    }
}

extern "C" void kernel_launch(void* const* d_in, const int* in_sizes, int n_in,
                              void* d_out, int out_size, void* d_ws, size_t ws_size,
                              hipStream_t stream) {
    const float* xyz1 = (const float*)d_in[0];
    const float* xyz2 = (const float*)d_in[1];
    ushort* preA  = (ushort*)d_ws;                        // 65536 * 64 B = 4 MB
    float4* preB4 = (float4*)(preA + (size_t)QTOTAL * 32);// 4 MB
    int*    out   = (int*)d_out;

    nnd_prep<<<QTOTAL / TPB, TPB, 0, stream>>>(xyz1, xyz2, preA, preB4, out);
    nnd_main<<<NBLK, TPB, 0, stream>>>(preA, preB4, out);
}

// Round 12
// 35.609 us; speedup vs baseline: 1.6063x; 1.0761x over previous
//
#include <hip/hip_runtime.h>

#define BATCH  8
#define NPTS   4096
#define TPB    256
#define QPT    8                    // queries per thread
#define QPB    (TPB * QPT)          // 2048 queries per block
#define QTILES (NPTS / QPB)         // 2 query tiles per batch
#define NSEG   32
#define SEG    (NPTS / NSEG)        // 128 ref points per block
#define SPAIR  (SEG / 2)            // 64 ref pairs per block
#define NPAIRS (NPTS / 2)           // 2048 ref pairs per batch cloud
#define HCLOUD (BATCH * NPAIRS)     // 16384 pairs per cloud
#define CLOUD  (BATCH * NPTS)       // 32768 points per cloud
#define QTOTAL (2 * CLOUD)          // 65536 outputs
#define NBLK   (2 * BATCH * QTILES * NSEG)   // 1024 blocks

typedef float v2f __attribute__((ext_vector_type(2)));
typedef float v4f __attribute__((ext_vector_type(4)));

// Guaranteed packed fp32 fma (2 distances/inst), all-VGPR operands (r5-proven).
__device__ inline v2f pk_fma(v2f a, v2f b, v2f c) {
    v2f d;
    asm("v_pk_fma_f32 %0, %1, %2, %3" : "=v"(d) : "v"(a), "v"(b), "v"(c));
    return d;
}
__device__ inline float fmin3(float a, float b, float c) {
    float d;
    asm("v_min3_f32 %0, %1, %2, %3" : "=v"(d) : "v"(a), "v"(b), "v"(c));
    return d;
}

// ws layout: [pre: 32768 pairs * 32 B = 1 MB][part: 16 dirb * 32 seg * 4096 * 4 B = 8 MB]
#define PART_OFF_FLOATS (2 * HCLOUD * 2 * 4)

// One thread per ref PAIR: pair-transposed preprocessed layout (r5-proven)
//   pre[2p]   = (-2x0, -2x1, -2y0, -2y1)
//   pre[2p+1] = (-2z0, -2z1,  w0,   w1)   w = x^2+y^2+z^2
__global__ __launch_bounds__(TPB) void nnd_prep(const float* __restrict__ xyz1,
                                                const float* __restrict__ xyz2,
                                                v4f* __restrict__ pre) {
    int i = blockIdx.x * TPB + (int)threadIdx.x;       // 0..32767 (pair id)
    const float* src = (i < HCLOUD) ? xyz1 : xyz2;
    int j = (i < HCLOUD) ? i : i - HCLOUD;
    const float* p = src + (size_t)j * 6;
    float x0 = p[0], y0 = p[1], z0 = p[2];
    float x1 = p[3], y1 = p[4], z1 = p[5];
    float w0 = x0 * x0 + y0 * y0 + z0 * z0;
    float w1 = x1 * x1 + y1 * y1 + z1 * z1;
    pre[2 * i + 0] = (v4f){-2.f * x0, -2.f * x1, -2.f * y0, -2.f * y1};
    pre[2 * i + 1] = (v4f){-2.f * z0, -2.f * z1, w0, w1};
}

// Main: block = (dir, b, qtile 2048, segment 128 pts). 64 ref pairs staged in
// LDS (2 KB); broadcast ds_read_b128 feeds 8 queries/thread -> DS amortized
// 4x vs round 5. Per jp: 2 DS + 24 pk_fma + 8 min3 = 1024 lane-distances.
// Plain coalesced partial stores (no atomics).
__global__ __launch_bounds__(TPB, 4) void nnd_main(const float* __restrict__ xyz1,
                                                   const float* __restrict__ xyz2,
                                                   const v4f* __restrict__ pre,
                                                   float* __restrict__ part) {
    // Bijective XCD swizzle (1024 = 8*128): contiguous logical slab per XCD.
    int bid = ((int)blockIdx.x & 7) * (NBLK / 8) + ((int)blockIdx.x >> 3);
    const int seg  = bid & (NSEG - 1);            // 5 bits
    const int tile = (bid >> 5) & (QTILES - 1);   // 1 bit
    const int b    = (bid >> 6) & (BATCH - 1);    // 3 bits
    const int dir  = bid >> 9;                    // 1 bit

    __shared__ v4f s[2 * SPAIR];                  // 128 x 16 B = 2 KB

    // Stage: 128 float4s, first 128 threads, coalesced.
    const size_t pairStart = (size_t)(dir == 0 ? 1 : 0) * HCLOUD
                           + (size_t)b * NPAIRS + (size_t)seg * SPAIR;
    if ((int)threadIdx.x < 2 * SPAIR)
        s[threadIdx.x] = pre[2 * pairStart + threadIdx.x];

    // 8 consecutive queries per thread: 24 floats = 6 aligned float4 loads.
    const float* q = (dir == 0) ? xyz1 : xyz2;
    const int n0 = tile * QPB + (int)threadIdx.x * QPT;
    const float4* qv = (const float4*)(q + ((size_t)b * NPTS + n0) * 3);
    float qf[24];
    #pragma unroll
    for (int v = 0; v < 6; ++v) {
        float4 t = qv[v];
        qf[4 * v + 0] = t.x; qf[4 * v + 1] = t.y;
        qf[4 * v + 2] = t.z; qf[4 * v + 3] = t.w;
    }

    float sqq[QPT];
    v2f qx2[QPT], qy2[QPT], qz2[QPT];
    #pragma unroll
    for (int k = 0; k < QPT; ++k) {
        float qx = qf[3 * k], qy = qf[3 * k + 1], qz = qf[3 * k + 2];
        sqq[k] = qx * qx + qy * qy + qz * qz;
        qx2[k] = (v2f){qx, qx};
        qy2[k] = (v2f){qy, qy};
        qz2[k] = (v2f){qz, qz};
    }

    float best[QPT];
    #pragma unroll
    for (int k = 0; k < QPT; ++k) best[k] = 1e30f;

    __syncthreads();

    #pragma unroll 4
    for (int p = 0; p < SPAIR; ++p) {
        v4f A = s[2 * p];                         // broadcast ds_read_b128
        v4f B = s[2 * p + 1];
        v2f x01 = __builtin_shufflevector(A, A, 0, 1);
        v2f y01 = __builtin_shufflevector(A, A, 2, 3);
        v2f z01 = __builtin_shufflevector(B, B, 0, 1);
        v2f w01 = __builtin_shufflevector(B, B, 2, 3);
        #pragma unroll
        for (int k = 0; k < QPT; ++k) {
            v2f e = pk_fma(x01, qx2[k], w01);
            e = pk_fma(y01, qy2[k], e);
            e = pk_fma(z01, qz2[k], e);
            best[k] = fmin3(best[k], e.x, e.y);
        }
    }

    // part[(dir*BATCH+b)][seg][n0..n0+7] — two aligned float4 stores.
    float* dst = part + ((size_t)(dir * BATCH + b) * NSEG + seg) * NPTS + n0;
    #pragma unroll
    for (int v = 0; v < 2; ++v) {
        float4 r;
        r.x = best[4 * v + 0] + sqq[4 * v + 0];
        r.y = best[4 * v + 1] + sqq[4 * v + 1];
        r.z = best[4 * v + 2] + sqq[4 * v + 2];
        r.w = best[4 * v + 3] + sqq[4 * v + 3];
        *(float4*)(dst + 4 * v) = r;
    }
}

// Fold the NSEG partials per query (coalesced column reads).
__global__ __launch_bounds__(TPB) void nnd_reduce(const float* __restrict__ part,
                                                  float* __restrict__ out) {
    int qid = blockIdx.x * TPB + (int)threadIdx.x;    // 0..65535
    int db = qid >> 12;                               // dir*BATCH+b
    int n  = qid & (NPTS - 1);
    const float* p = part + (size_t)db * NSEG * NPTS + n;
    float m = p[0];
    #pragma unroll
    for (int sgm = 1; sgm < NSEG; ++sgm) m = fminf(m, p[(size_t)sgm * NPTS]);
    out[qid] = m;
}

extern "C" void kernel_launch(void* const* d_in, const int* in_sizes, int n_in,
                              void* d_out, int out_size, void* d_ws, size_t ws_size,
                              hipStream_t stream) {
    const float* xyz1 = (const float*)d_in[0];
    const float* xyz2 = (const float*)d_in[1];
    v4f*   pre  = (v4f*)d_ws;
    float* part = (float*)d_ws + PART_OFF_FLOATS;
    float* out  = (float*)d_out;

    nnd_prep<<<(2 * HCLOUD) / TPB, TPB, 0, stream>>>(xyz1, xyz2, pre);
    nnd_main<<<NBLK, TPB, 0, stream>>>(xyz1, xyz2, pre, part);
    nnd_reduce<<<QTOTAL / TPB, TPB, 0, stream>>>(part, out);
}